// Round 2
// baseline (1492.426 us; speedup 1.0000x reference)
//
#include <hip/hip_runtime.h>
#include <hip/hip_bf16.h>

#define NN 100000
#define NE 3200000
#define NG 4096
#define NB 256          // blocks in hist/pairs; NE/NB = 12500 exactly
#define NBK 782         // coarse buckets of 128 nodes
#define NCHUNK 7        // src chunks of 16384 nodes (2 MB of hs each)
#define CHSH 14

typedef unsigned short ushort_t;
typedef short short8 __attribute__((ext_vector_type(8)));
typedef float floatx4 __attribute__((ext_vector_type(4)));

__device__ __forceinline__ float bf2f(unsigned short u){
  union{unsigned int i; float f;} x; x.i = ((unsigned)u)<<16; return x.f;
}
__device__ __forceinline__ ushort_t f2bf(float f){
  union{float f; unsigned int i;} x; x.f = f;
  unsigned int r = x.i + 0x7fff + ((x.i >> 16) & 1);
  return (ushort_t)(r >> 16);
}

// ---------------- CSR build: hierarchical counting sort ----------------

__global__ __launch_bounds__(512) void k_hist(const int* __restrict__ ei, int* __restrict__ histT){
  __shared__ int lh[NBK];
  int b = blockIdx.x, t = threadIdx.x;
  for (int k=t; k<NBK; k+=512) lh[k]=0;
  __syncthreads();
  int e0 = b*(NE/NB);
  for (int e=e0+t; e<e0+(NE/NB); e+=512) atomicAdd(&lh[ei[NE+e]>>7], 1);
  __syncthreads();
  for (int k=t; k<NBK; k+=512) histT[(size_t)k*NB+b] = lh[k];
}

__global__ __launch_bounds__(256) void k_scanA(int* __restrict__ histT, int* __restrict__ total){
  int wv = blockIdx.x*4 + (threadIdx.x>>6);
  int lane = threadIdx.x & 63;
  if (wv >= NBK) return;
  int* row = histT + (size_t)wv*NB;
  int carry = 0;
  #pragma unroll
  for (int ch=0; ch<NB/64; ++ch){
    int a = row[ch*64+lane];
    int inc = a;
    for (int off=1; off<64; off<<=1){
      int x = __shfl_up(inc, off, 64);
      if (lane >= off) inc += x;
    }
    row[ch*64+lane] = carry + inc - a;       // exclusive
    carry += __shfl(inc, 63, 64);
  }
  if (lane==0) total[wv] = carry;
}

__global__ void k_scanB(const int* __restrict__ total, int* __restrict__ base){
  __shared__ int lds[1024];
  int t = threadIdx.x;
  int v = (t < NBK)? total[t] : 0;
  lds[t] = v; __syncthreads();
  for (int off=1; off<1024; off<<=1){
    int x = (t>=off)? lds[t-off] : 0;
    __syncthreads();
    lds[t] += x;
    __syncthreads();
  }
  if (t < NBK)      base[t]   = lds[t]-v;
  if (t == NBK-1)   base[NBK] = lds[t];      // == NE
}

__global__ __launch_bounds__(512) void k_pairs(const int* __restrict__ ei,
    const int* __restrict__ histT, const int* __restrict__ base,
    int* __restrict__ pairs){
  __shared__ int cur[NBK];
  int b = blockIdx.x, t = threadIdx.x;
  for (int k=t; k<NBK; k+=512) cur[k] = base[k] + histT[(size_t)k*NB + b];
  __syncthreads();
  int e0 = b*(NE/NB);
  for (int e=e0+t; e<e0+(NE/NB); e+=512){
    int src = ei[e], dst = ei[NE+e];
    int p = atomicAdd(&cur[dst>>7], 1);      // LDS atomic
    pairs[p] = (src << 7) | (dst & 127);
  }
}

// per-bucket 10-bit counting sort ((dst&127)<<3 | src_chunk) -> csr with each
// row's entries ordered by src chunk (enables register-cursor chunked gather).
// Emits plain colptr + dinv; no extra per-chunk offset array needed.
__global__ __launch_bounds__(256) void k_fine(const int* __restrict__ pairs,
    const int* __restrict__ base, int* __restrict__ csr,
    int* __restrict__ colptr, float* __restrict__ dinv){
  __shared__ int cnt[1024], off[1024], part[256];
  int k = blockIdx.x, t = threadIdx.x;
  for (int i=t; i<1024; i+=256) cnt[i]=0;
  __syncthreads();
  int s = base[k], e = base[k+1];
  for (int i=s+t; i<e; i+=256){
    int u = pairs[i];
    atomicAdd(&cnt[((u & 127) << 3) | ((u >> 7) >> CHSH)], 1);
  }
  __syncthreads();
  // exclusive scan of 1024 counters: 4 per thread + 256-wide Hillis-Steele
  int c0=cnt[t*4], c1=cnt[t*4+1], c2=cnt[t*4+2], c3=cnt[t*4+3];
  int loc = c0+c1+c2+c3;
  part[t] = loc;
  __syncthreads();
  for (int o=1; o<256; o<<=1){
    int x = (t>=o)? part[t-o] : 0;
    __syncthreads();
    part[t] += x;
    __syncthreads();
  }
  int ex = part[t] - loc;
  off[t*4]   = ex;
  off[t*4+1] = ex + c0;
  off[t*4+2] = ex + c0 + c1;
  off[t*4+3] = ex + c0 + c1 + c2;
  __syncthreads();
  int node0 = k*128;
  if (t < 128 && node0+t < NN){
    int st = off[t*8];                        // row start (chunk-0 start)
    int en = (t<127)? off[(t+1)*8] : (e-s);   // row end
    colptr[node0+t] = s + st;
    dinv[node0+t]   = rsqrtf((float)(en-st) + 1.0f);
  }
  if (k == NBK-1 && t == 0) colptr[NN] = NE;
  __syncthreads();
  // off[] doubles as scatter cursors now (all reads of off are done)
  for (int i=s+t; i<e; i+=256){
    int u = pairs[i];
    int src = u >> 7;
    int p = s + atomicAdd(&off[((u & 127) << 3) | (src >> CHSH)], 1);
    csr[p] = src;
  }
}

// ---------------- MFMA GEMM layer 0: hs = bf16( (x @ W) * dinv ), K=128 ----------------

__global__ __launch_bounds__(256) void k_gemm0m(const float* __restrict__ x,
    const float* __restrict__ W, const float* __restrict__ dinv,
    ushort_t* __restrict__ hs){
  __shared__ __attribute__((aligned(16))) ushort_t Wt[64*136];
  int t = threadIdx.x;
  for (int i=t; i<128*64; i+=256){
    int k = i>>6, n = i&63;
    Wt[n*136 + k] = f2bf(W[i]);
  }
  __syncthreads();
  int lane = t & 63, wv = t >> 6;
  int n0 = lane & 15, quad = lane >> 4;
  int r0 = blockIdx.x*64 + wv*16;
  int row = r0 + n0;
  int rowc = (row < NN)? row : NN-1;
  const float* xr = x + (size_t)rowc*128 + quad*8;
  floatx4 acc[4] = {{0,0,0,0},{0,0,0,0},{0,0,0,0},{0,0,0,0}};
  #pragma unroll
  for (int ks=0; ks<4; ++ks){
    float4 a01 = *(const float4*)(xr + ks*32);
    float4 a23 = *(const float4*)(xr + ks*32 + 4);
    short8 af;
    af[0]=(short)f2bf(a01.x); af[1]=(short)f2bf(a01.y);
    af[2]=(short)f2bf(a01.z); af[3]=(short)f2bf(a01.w);
    af[4]=(short)f2bf(a23.x); af[5]=(short)f2bf(a23.y);
    af[6]=(short)f2bf(a23.z); af[7]=(short)f2bf(a23.w);
    #pragma unroll
    for (int tl=0; tl<4; ++tl){
      short8 bf = *(const short8*)(&Wt[(tl*16+n0)*136 + ks*32 + quad*8]);
      acc[tl] = __builtin_amdgcn_mfma_f32_16x16x32_bf16(af, bf, acc[tl], 0, 0, 0);
    }
  }
  #pragma unroll
  for (int reg=0; reg<4; ++reg){
    int rr = r0 + quad*4 + reg;
    if (rr < NN){
      float dv = dinv[rr];
      #pragma unroll
      for (int tl=0; tl<4; ++tl)
        hs[(size_t)rr*64 + tl*16 + n0] = f2bf(acc[tl][reg]*dv);
    }
  }
}

// ---------------- MFMA GEMM layers 1/2 with fused BN+ReLU on A, K=64 ----------------

__global__ __launch_bounds__(256) void k_gemmSm(const float* __restrict__ h,
    const float* __restrict__ W, const float* __restrict__ coeff,
    const float* __restrict__ dinv, ushort_t* __restrict__ hs){
  __shared__ __attribute__((aligned(16))) ushort_t Wt[64*72];
  int t = threadIdx.x;
  for (int i=t; i<64*64; i+=256){
    int k = i>>6, n = i&63;
    Wt[n*72 + k] = f2bf(W[i]);
  }
  __syncthreads();
  int lane = t & 63, wv = t >> 6;
  int n0 = lane & 15, quad = lane >> 4;
  int r0 = blockIdx.x*64 + wv*16;
  int row = r0 + n0;
  int rowc = (row < NN)? row : NN-1;
  const float* hr = h + (size_t)rowc*64 + quad*8;
  floatx4 acc[4] = {{0,0,0,0},{0,0,0,0},{0,0,0,0},{0,0,0,0}};
  #pragma unroll
  for (int ks=0; ks<2; ++ks){
    float4 a01 = *(const float4*)(hr + ks*32);
    float4 a23 = *(const float4*)(hr + ks*32 + 4);
    const float* cA = coeff + ks*32 + quad*8;
    float4 ca0 = *(const float4*)(cA),      ca1 = *(const float4*)(cA+4);
    float4 cb0 = *(const float4*)(cA+64),   cb1 = *(const float4*)(cA+68);
    short8 af;
    af[0]=(short)f2bf(fmaxf(fmaf(a01.x,ca0.x,cb0.x),0.f));
    af[1]=(short)f2bf(fmaxf(fmaf(a01.y,ca0.y,cb0.y),0.f));
    af[2]=(short)f2bf(fmaxf(fmaf(a01.z,ca0.z,cb0.z),0.f));
    af[3]=(short)f2bf(fmaxf(fmaf(a01.w,ca0.w,cb0.w),0.f));
    af[4]=(short)f2bf(fmaxf(fmaf(a23.x,ca1.x,cb1.x),0.f));
    af[5]=(short)f2bf(fmaxf(fmaf(a23.y,ca1.y,cb1.y),0.f));
    af[6]=(short)f2bf(fmaxf(fmaf(a23.z,ca1.z,cb1.z),0.f));
    af[7]=(short)f2bf(fmaxf(fmaf(a23.w,ca1.w,cb1.w),0.f));
    #pragma unroll
    for (int tl=0; tl<4; ++tl){
      short8 bf = *(const short8*)(&Wt[(tl*16+n0)*72 + ks*32 + quad*8]);
      acc[tl] = __builtin_amdgcn_mfma_f32_16x16x32_bf16(af, bf, acc[tl], 0, 0, 0);
    }
  }
  #pragma unroll
  for (int reg=0; reg<4; ++reg){
    int rr = r0 + quad*4 + reg;
    if (rr < NN){
      float dv = dinv[rr];
      #pragma unroll
      for (int tl=0; tl<4; ++tl)
        hs[(size_t)rr*64 + tl*16 + n0] = f2bf(acc[tl][reg]*dv);
    }
  }
}

// ---------------- src-chunked pull-aggregation, register cursors ----------------
// Rows are chunk-sorted, so per-node cursors advance monotonically across the
// 7 chunk passes; accumulators stay in registers the whole time. Each 2 MB hs
// chunk is gathered by all waves concurrently while L2-resident. All control
// flow is wave-uniform (whole wave shares one node row; lanes = channels).
// blockIdx&7 pins each XCD (round-robin dispatch) to a contiguous 1/8 of dst
// nodes so its csr slice (~1.6 MB) stays L2-resident across chunk passes.

__global__ __launch_bounds__(256) void k_aggregate(const ushort_t* __restrict__ hs,
    const int* __restrict__ colptr, const int* __restrict__ csr,
    const float* __restrict__ dinv, const float* __restrict__ bias,
    float* __restrict__ out, float* __restrict__ stats){
  int t = threadIdx.x; int c = t & 63;
  int b = blockIdx.x;
  int xcd = b & 7;
  int local = (b>>3)*4 + (t>>6);             // 0..1023 (wave-uniform)
  int vb = xcd * (NN/8);                     // 12500 nodes per XCD slice
  float bc = bias[c];
  float acc[13];
  int E[13], Eend[13];
  #pragma unroll
  for (int j=0; j<13; ++j){
    int idx = local + j*1024;
    bool ok = idx < NN/8;
    int v = __builtin_amdgcn_readfirstlane(vb + (ok? idx : 0));
    float sv = bf2f(hs[(size_t)v*64 + c]);   // self-loop term
    acc[j] = ok? sv : 0.f;
    int e0 = colptr[v];
    E[j]    = e0;
    Eend[j] = ok? colptr[v+1] : e0;          // empty row if inactive
  }
  for (int ch=0; ch<NCHUNK; ++ch){
    #pragma unroll
    for (int j=0; j<13; ++j){
      int e = E[j], e1 = Eend[j];
      float a = 0.f;
      while (e < e1){
        if (e+4 <= e1){
          int i0=csr[e], i1=csr[e+1], i2=csr[e+2], i3=csr[e+3];
          if ((i3>>CHSH) == ch){             // sorted: all 4 in this chunk
            float f0=bf2f(hs[(size_t)i0*64+c]), f1=bf2f(hs[(size_t)i1*64+c]);
            float f2=bf2f(hs[(size_t)i2*64+c]), f3=bf2f(hs[(size_t)i3*64+c]);
            a += (f0+f1)+(f2+f3);
            e += 4; continue;
          }
        }
        int i0 = csr[e];
        if ((i0>>CHSH) != ch) break;         // next chunk starts here
        a += bf2f(hs[(size_t)i0*64+c]);
        ++e;
      }
      acc[j] += a;
      E[j] = e;
    }
  }
  float s1 = 0.f, s2 = 0.f;
  #pragma unroll
  for (int j=0; j<13; ++j){
    int idx = local + j*1024;
    if (idx < NN/8){
      int v = vb + idx;
      float o = acc[j]*dinv[v] + bc;
      __builtin_nontemporal_store(o, &out[(size_t)v*64+c]);   // keep L2 for hs
      s1 += o; s2 += o*o;
    }
  }
  __shared__ float l1[256], l2[256];
  l1[t]=s1; l2[t]=s2; __syncthreads();
  if (t < 64){
    float a1 = l1[t]+l1[t+64]+l1[t+128]+l1[t+192];
    float a2 = l2[t]+l2[t+64]+l2[t+128]+l2[t+192];
    float* rep = stats + (size_t)(blockIdx.x & 31)*128;
    atomicAdd(&rep[t],    a1);
    atomicAdd(&rep[64+t], a2);
  }
}

// ---------------- BN coeff ----------------

__global__ void k_bncoeff(const float* __restrict__ stats, const float* __restrict__ g,
                          const float* __restrict__ be, float cnt, float* __restrict__ coeff){
  int c = threadIdx.x;                       // 64
  float s1=0.f, s2=0.f;
  for (int r=0;r<32;++r){ s1 += stats[r*128+c]; s2 += stats[r*128+64+c]; }
  float mu  = s1/cnt;
  float var = s2/cnt - mu*mu;
  float a   = g[c]*rsqrtf(var + 1e-5f);
  coeff[c]    = a;
  coeff[64+c] = be[c] - mu*a;
}

// ---------------- fused pool (bounds search + BN+ReLU + mean) + W1 matmul + stats ----------------

__global__ __launch_bounds__(256) void k_poolhead(const float* __restrict__ h,
    const int* __restrict__ batch, const float* __restrict__ cf,
    const float* __restrict__ W1, const float* __restrict__ b1,
    float* __restrict__ tbuf, float* __restrict__ stats){
  __shared__ float pl[256];
  int t=threadIdx.x; int c=t&63; int wv=t>>6;
  int g = __builtin_amdgcn_readfirstlane((int)(blockIdx.x*4 + wv));
  int lo=0, hi=NN;
  while (lo<hi){ int mid=(lo+hi)>>1; if (batch[mid]<g) lo=mid+1; else hi=mid; }
  int s = lo;
  hi = NN;
  while (lo<hi){ int mid=(lo+hi)>>1; if (batch[mid]<g+1) lo=mid+1; else hi=mid; }
  int e = lo;
  float a = cf[c], d = cf[64+c];
  float acc=0.f;
  for (int v=s; v<e; ++v) acc += fmaxf(fmaf(h[(size_t)v*64+c], a, d), 0.f);
  float inv = 1.0f / fmaxf((float)(e-s), 1.0f);
  pl[wv*64 + c] = acc*inv;
  __syncthreads();
  const float* p = pl + wv*64;
  float tk = b1[c];
  #pragma unroll 4
  for (int k=0;k<64;++k) tk = fmaf(p[k], W1[k*64+c], tk);
  tbuf[(size_t)g*64+c] = tk;
  float* rep = stats + (size_t)(blockIdx.x & 31)*128;
  atomicAdd(&rep[c],    tk);
  atomicAdd(&rep[64+c], tk*tk);
}

__global__ __launch_bounds__(256) void k_final(const float* __restrict__ tbuf, const float* __restrict__ gcf,
                                               const float* __restrict__ W2, const float* __restrict__ b2,
                                               float* __restrict__ out){
  int t=threadIdx.x; int c=t&63;
  int g = blockIdx.x*4 + (t>>6);
  float tv = tbuf[(size_t)g*64+c];
  float z  = fmaxf(fmaf(tv, gcf[c], gcf[64+c]), 0.f);
  float p  = z * W2[c];
  #pragma unroll
  for (int o=32;o>0;o>>=1) p += __shfl_xor(p, o, 64);
  if (c==0) out[g] = p + b2[0];
}

// ---------------- launch ----------------

extern "C" void kernel_launch(void* const* d_in, const int* in_sizes, int n_in,
                              void* d_out, int out_size, void* d_ws, size_t ws_size,
                              hipStream_t stream) {
  const float* x    = (const float*)d_in[0];
  const int*   ei   = (const int*)d_in[1];
  const int*   batch= (const int*)d_in[2];
  const float* Wc0=(const float*)d_in[3],  *bc0=(const float*)d_in[4];
  const float* g0 =(const float*)d_in[5],  *be0=(const float*)d_in[6];
  const float* Wc1=(const float*)d_in[7],  *bc1=(const float*)d_in[8];
  const float* g1 =(const float*)d_in[9],  *be1=(const float*)d_in[10];
  const float* Wc2=(const float*)d_in[11], *bc2=(const float*)d_in[12];
  const float* g2 =(const float*)d_in[13], *be2=(const float*)d_in[14];
  const float* W1 =(const float*)d_in[15], *b1 =(const float*)d_in[16];
  const float* gf =(const float*)d_in[17], *bf_=(const float*)d_in[18];
  const float* W2 =(const float*)d_in[19], *b2 =(const float*)d_in[20];
  float* out = (float*)d_out;

  char* w = (char*)d_ws;
  float*    stats  = (float*)   (w + 0);          // 4 sets x 32 reps x 128 f [zeroed]
  int*      total  = (int*)     (w + 65536);      // NBK
  int*      base   = (int*)     (w + 68736);      // NBK+1
  int*      colptr = (int*)     (w + 71936);      // NN+1
  float*    dinv   = (float*)   (w + 471952);
  float*    coeff  = (float*)   (w + 871952);
  float*    gcoeff = (float*)   (w + 872464);
  float*    pooled = (float*)   (w + 872976);     // NG x 64
  int*      csr    = (int*)     (w + 1921552);    // NE ints
  ushort_t* bufA   = (ushort_t*)(w + 14721552);   // hs bf16 row-major
  float*    bufB   = (float*)   (w + 27521552);   // h fp32 row-major (pre-BN); ends ~53.1 MB
  int*      histT  = csr;                         // alias: dead before k_fine writes csr
  int*      pairs  = (int*)bufB;                  // alias: dead before bufB first write

  hipMemsetAsync(stats, 0, 65536, stream);

  // CSR build (no global atomics), rows chunk-sorted by src>>14
  k_hist <<<NB,  512,  0, stream>>>(ei, histT);
  k_scanA<<<196, 256,  0, stream>>>(histT, total);
  k_scanB<<<1,   1024, 0, stream>>>(total, base);
  k_pairs<<<NB,  512,  0, stream>>>(ei, histT, base, pairs);
  k_fine <<<NBK, 256,  0, stream>>>(pairs, base, csr, colptr, dinv);

  // layer 0
  k_gemm0m<<<1563, 256, 0, stream>>>(x, Wc0, dinv, bufA);
  k_aggregate<<<2048, 256, 0, stream>>>(bufA, colptr, csr, dinv, bc0, bufB, stats + 0*4096);
  k_bncoeff<<<1, 64, 0, stream>>>(stats + 0*4096, g0, be0, (float)NN, coeff);
  // layer 1 (BN+ReLU of layer 0 fused into A-path)
  k_gemmSm<<<1563, 256, 0, stream>>>(bufB, Wc1, coeff, dinv, bufA);
  k_aggregate<<<2048, 256, 0, stream>>>(bufA, colptr, csr, dinv, bc1, bufB, stats + 1*4096);
  k_bncoeff<<<1, 64, 0, stream>>>(stats + 1*4096, g1, be1, (float)NN, coeff);
  // layer 2
  k_gemmSm<<<1563, 256, 0, stream>>>(bufB, Wc2, coeff, dinv, bufA);
  k_aggregate<<<2048, 256, 0, stream>>>(bufA, colptr, csr, dinv, bc2, bufB, stats + 2*4096);
  k_bncoeff<<<1, 64, 0, stream>>>(stats + 2*4096, g2, be2, (float)NN, coeff);

  // head (BN+ReLU of layer 2 + bounds search + mean + W1 fused)
  k_poolhead<<<NG/4, 256, 0, stream>>>(bufB, batch, coeff, W1, b1, pooled, stats + 3*4096);
  k_bncoeff<<<1, 64, 0, stream>>>(stats + 3*4096, gf, bf_, (float)NG, gcoeff);
  k_final<<<NG/4, 256, 0, stream>>>(pooled, gcoeff, W2, b2, out);
}

// Round 3
// 952.126 us; speedup vs baseline: 1.5675x; 1.5675x over previous
//
#include <hip/hip_runtime.h>
#include <hip/hip_bf16.h>

#define NN 100000
#define NE 3200000
#define NG 4096
#define NB 256          // blocks in hist/pairs; NE/NB = 12500 exactly
#define NBK 782         // coarse buckets of 128 nodes
#define NCHUNK 7        // src chunks of 16384 nodes (2 MB of hs each)
#define CHSH 14

typedef unsigned short ushort_t;
typedef short short8 __attribute__((ext_vector_type(8)));
typedef float floatx4 __attribute__((ext_vector_type(4)));

__device__ __forceinline__ float bf2f(unsigned short u){
  union{unsigned int i; float f;} x; x.i = ((unsigned)u)<<16; return x.f;
}
__device__ __forceinline__ ushort_t f2bf(float f){
  union{float f; unsigned int i;} x; x.f = f;
  unsigned int r = x.i + 0x7fff + ((x.i >> 16) & 1);
  return (ushort_t)(r >> 16);
}

// ---------------- CSR build: hierarchical counting sort ----------------

__global__ __launch_bounds__(512) void k_hist(const int* __restrict__ ei, int* __restrict__ histT){
  __shared__ int lh[NBK];
  int b = blockIdx.x, t = threadIdx.x;
  for (int k=t; k<NBK; k+=512) lh[k]=0;
  __syncthreads();
  int e0 = b*(NE/NB);
  for (int e=e0+t; e<e0+(NE/NB); e+=512) atomicAdd(&lh[ei[NE+e]>>7], 1);
  __syncthreads();
  for (int k=t; k<NBK; k+=512) histT[(size_t)k*NB+b] = lh[k];
}

__global__ __launch_bounds__(256) void k_scanA(int* __restrict__ histT, int* __restrict__ total){
  int wv = blockIdx.x*4 + (threadIdx.x>>6);
  int lane = threadIdx.x & 63;
  if (wv >= NBK) return;
  int* row = histT + (size_t)wv*NB;
  int carry = 0;
  #pragma unroll
  for (int ch=0; ch<NB/64; ++ch){
    int a = row[ch*64+lane];
    int inc = a;
    for (int off=1; off<64; off<<=1){
      int x = __shfl_up(inc, off, 64);
      if (lane >= off) inc += x;
    }
    row[ch*64+lane] = carry + inc - a;       // exclusive
    carry += __shfl(inc, 63, 64);
  }
  if (lane==0) total[wv] = carry;
}

__global__ void k_scanB(const int* __restrict__ total, int* __restrict__ base){
  __shared__ int lds[1024];
  int t = threadIdx.x;
  int v = (t < NBK)? total[t] : 0;
  lds[t] = v; __syncthreads();
  for (int off=1; off<1024; off<<=1){
    int x = (t>=off)? lds[t-off] : 0;
    __syncthreads();
    lds[t] += x;
    __syncthreads();
  }
  if (t < NBK)      base[t]   = lds[t]-v;
  if (t == NBK-1)   base[NBK] = lds[t];      // == NE
}

__global__ __launch_bounds__(512) void k_pairs(const int* __restrict__ ei,
    const int* __restrict__ histT, const int* __restrict__ base,
    int* __restrict__ pairs){
  __shared__ int cur[NBK];
  int b = blockIdx.x, t = threadIdx.x;
  for (int k=t; k<NBK; k+=512) cur[k] = base[k] + histT[(size_t)k*NB + b];
  __syncthreads();
  int e0 = b*(NE/NB);
  for (int e=e0+t; e<e0+(NE/NB); e+=512){
    int src = ei[e], dst = ei[NE+e];
    int p = atomicAdd(&cur[dst>>7], 1);      // LDS atomic
    pairs[p] = (src << 7) | (dst & 127);
  }
}

// per-bucket 10-bit counting sort ((dst&127)<<3 | src_chunk) -> csr stored as
// CHUNK-RELATIVE ushort (src & 16383); emits colptrC[v*8+ch] chunk segment
// starts ([v*8+7] = row end) and dinv. Counted loops downstream -> full MLP.
__global__ __launch_bounds__(256) void k_fine(const int* __restrict__ pairs,
    const int* __restrict__ base, ushort_t* __restrict__ csr,
    int* __restrict__ colptrC, float* __restrict__ dinv){
  __shared__ int cnt[1024], off[1024], part[256];
  int k = blockIdx.x, t = threadIdx.x;
  for (int i=t; i<1024; i+=256) cnt[i]=0;
  __syncthreads();
  int s = base[k], e = base[k+1];
  for (int i=s+t; i<e; i+=256){
    int u = pairs[i];
    atomicAdd(&cnt[((u & 127) << 3) | ((u >> 7) >> CHSH)], 1);
  }
  __syncthreads();
  // exclusive scan of 1024 counters: 4 per thread + 256-wide Hillis-Steele
  int c0=cnt[t*4], c1=cnt[t*4+1], c2=cnt[t*4+2], c3=cnt[t*4+3];
  int loc = c0+c1+c2+c3;
  part[t] = loc;
  __syncthreads();
  for (int o=1; o<256; o<<=1){
    int x = (t>=o)? part[t-o] : 0;
    __syncthreads();
    part[t] += x;
    __syncthreads();
  }
  int ex = part[t] - loc;
  off[t*4]   = ex;
  off[t*4+1] = ex + c0;
  off[t*4+2] = ex + c0 + c1;
  off[t*4+3] = ex + c0 + c1 + c2;
  __syncthreads();
  int node0 = k*128;
  // chunk 7 never occurs (src>>14 <= 6), so off[d*8+7] == row end (even d=127)
  for (int i=t; i<1024; i+=256){
    int d = i>>3;
    if (node0 + d < NN) colptrC[(size_t)(node0+d)*8 + (i&7)] = s + off[i];
  }
  if (t < 128 && node0+t < NN){
    int st = off[t*8];
    int en = (t<127)? off[(t+1)*8] : (e-s);
    dinv[node0+t] = rsqrtf((float)(en-st) + 1.0f);
  }
  __syncthreads();
  // off[] doubles as scatter cursors now (all reads of off are done)
  for (int i=s+t; i<e; i+=256){
    int u = pairs[i];
    int src = u >> 7;
    int p = s + atomicAdd(&off[((u & 127) << 3) | (src >> CHSH)], 1);
    csr[p] = (ushort_t)(src & ((1<<CHSH)-1));   // chunk-relative
  }
}

// ---------------- MFMA GEMM layer 0: hs = bf16( (x @ W) * dinv ), K=128 ----------------

__global__ __launch_bounds__(256) void k_gemm0m(const float* __restrict__ x,
    const float* __restrict__ W, const float* __restrict__ dinv,
    ushort_t* __restrict__ hs){
  __shared__ __attribute__((aligned(16))) ushort_t Wt[64*136];
  int t = threadIdx.x;
  for (int i=t; i<128*64; i+=256){
    int k = i>>6, n = i&63;
    Wt[n*136 + k] = f2bf(W[i]);
  }
  __syncthreads();
  int lane = t & 63, wv = t >> 6;
  int n0 = lane & 15, quad = lane >> 4;
  int r0 = blockIdx.x*64 + wv*16;
  int row = r0 + n0;
  int rowc = (row < NN)? row : NN-1;
  const float* xr = x + (size_t)rowc*128 + quad*8;
  floatx4 acc[4] = {{0,0,0,0},{0,0,0,0},{0,0,0,0},{0,0,0,0}};
  #pragma unroll
  for (int ks=0; ks<4; ++ks){
    float4 a01 = *(const float4*)(xr + ks*32);
    float4 a23 = *(const float4*)(xr + ks*32 + 4);
    short8 af;
    af[0]=(short)f2bf(a01.x); af[1]=(short)f2bf(a01.y);
    af[2]=(short)f2bf(a01.z); af[3]=(short)f2bf(a01.w);
    af[4]=(short)f2bf(a23.x); af[5]=(short)f2bf(a23.y);
    af[6]=(short)f2bf(a23.z); af[7]=(short)f2bf(a23.w);
    #pragma unroll
    for (int tl=0; tl<4; ++tl){
      short8 bf = *(const short8*)(&Wt[(tl*16+n0)*136 + ks*32 + quad*8]);
      acc[tl] = __builtin_amdgcn_mfma_f32_16x16x32_bf16(af, bf, acc[tl], 0, 0, 0);
    }
  }
  #pragma unroll
  for (int reg=0; reg<4; ++reg){
    int rr = r0 + quad*4 + reg;
    if (rr < NN){
      float dv = dinv[rr];
      #pragma unroll
      for (int tl=0; tl<4; ++tl)
        hs[(size_t)rr*64 + tl*16 + n0] = f2bf(acc[tl][reg]*dv);
    }
  }
}

// ---------------- MFMA GEMM layers 1/2 with fused BN+ReLU on A, K=64 ----------------

__global__ __launch_bounds__(256) void k_gemmSm(const float* __restrict__ h,
    const float* __restrict__ W, const float* __restrict__ coeff,
    const float* __restrict__ dinv, ushort_t* __restrict__ hs){
  __shared__ __attribute__((aligned(16))) ushort_t Wt[64*72];
  int t = threadIdx.x;
  for (int i=t; i<64*64; i+=256){
    int k = i>>6, n = i&63;
    Wt[n*72 + k] = f2bf(W[i]);
  }
  __syncthreads();
  int lane = t & 63, wv = t >> 6;
  int n0 = lane & 15, quad = lane >> 4;
  int r0 = blockIdx.x*64 + wv*16;
  int row = r0 + n0;
  int rowc = (row < NN)? row : NN-1;
  const float* hr = h + (size_t)rowc*64 + quad*8;
  floatx4 acc[4] = {{0,0,0,0},{0,0,0,0},{0,0,0,0},{0,0,0,0}};
  #pragma unroll
  for (int ks=0; ks<2; ++ks){
    float4 a01 = *(const float4*)(hr + ks*32);
    float4 a23 = *(const float4*)(hr + ks*32 + 4);
    const float* cA = coeff + ks*32 + quad*8;
    float4 ca0 = *(const float4*)(cA),      ca1 = *(const float4*)(cA+4);
    float4 cb0 = *(const float4*)(cA+64),   cb1 = *(const float4*)(cA+68);
    short8 af;
    af[0]=(short)f2bf(fmaxf(fmaf(a01.x,ca0.x,cb0.x),0.f));
    af[1]=(short)f2bf(fmaxf(fmaf(a01.y,ca0.y,cb0.y),0.f));
    af[2]=(short)f2bf(fmaxf(fmaf(a01.z,ca0.z,cb0.z),0.f));
    af[3]=(short)f2bf(fmaxf(fmaf(a01.w,ca0.w,cb0.w),0.f));
    af[4]=(short)f2bf(fmaxf(fmaf(a23.x,ca1.x,cb1.x),0.f));
    af[5]=(short)f2bf(fmaxf(fmaf(a23.y,ca1.y,cb1.y),0.f));
    af[6]=(short)f2bf(fmaxf(fmaf(a23.z,ca1.z,cb1.z),0.f));
    af[7]=(short)f2bf(fmaxf(fmaf(a23.w,ca1.w,cb1.w),0.f));
    #pragma unroll
    for (int tl=0; tl<4; ++tl){
      short8 bf = *(const short8*)(&Wt[(tl*16+n0)*72 + ks*32 + quad*8]);
      acc[tl] = __builtin_amdgcn_mfma_f32_16x16x32_bf16(af, bf, acc[tl], 0, 0, 0);
    }
  }
  #pragma unroll
  for (int reg=0; reg<4; ++reg){
    int rr = r0 + quad*4 + reg;
    if (rr < NN){
      float dv = dinv[rr];
      #pragma unroll
      for (int tl=0; tl<4; ++tl)
        hs[(size_t)rr*64 + tl*16 + n0] = f2bf(acc[tl][reg]*dv);
    }
  }
}

// ---------------- src-chunked pull-aggregation, counted segments ----------------
// colptrC gives exact per-(node,chunk) bounds -> plain counted inner loops
// (full MLP, no data-dependent branches). Cursors E[j] carry across chunks so
// only ONE uniform colptrC load per (node,chunk). Each 2 MB hs chunk is
// gathered by all waves concurrently while L2-resident; blockIdx&7 pins each
// XCD to a contiguous 1/8 of dst nodes (csr slice ~0.8 MB stays L2-resident).

__global__ __launch_bounds__(256) void k_aggregate(const ushort_t* __restrict__ hs,
    const int* __restrict__ colptrC, const ushort_t* __restrict__ csr,
    const float* __restrict__ dinv, const float* __restrict__ bias,
    float* __restrict__ out, float* __restrict__ stats){
  int t = threadIdx.x; int c = t & 63;
  int b = blockIdx.x;
  int xcd = b & 7;
  int local = (b>>3)*4 + (t>>6);             // 0..1023 (wave-uniform)
  int vb = xcd * (NN/8);                     // 12500 nodes per XCD slice
  float bc = bias[c];
  float acc[13];
  int E[13];
  #pragma unroll
  for (int j=0; j<13; ++j){
    int idx = local + j*1024;
    bool ok = idx < NN/8;
    int v = __builtin_amdgcn_readfirstlane(vb + (ok? idx : 0));
    float sv = bf2f(hs[(size_t)v*64 + c]);   // self-loop term
    acc[j] = ok? sv : 0.f;
    E[j] = colptrC[(size_t)v*8];             // row start
  }
  for (int ch=0; ch<NCHUNK; ++ch){
    const ushort_t* hsc = hs + (((size_t)ch) << CHSH)*64;
    #pragma unroll
    for (int j=0; j<13; ++j){
      int idx = local + j*1024;
      bool ok = idx < NN/8;
      int v = __builtin_amdgcn_readfirstlane(vb + (ok? idx : 0));
      int e1 = colptrC[(size_t)v*8 + ch + 1];
      int e = ok? E[j] : e1;
      float a = 0.f;
      for (; e+4 <= e1; e += 4){             // counted: independent gathers
        int i0=csr[e], i1=csr[e+1], i2=csr[e+2], i3=csr[e+3];
        float f0=bf2f(hsc[(size_t)i0*64+c]), f1=bf2f(hsc[(size_t)i1*64+c]);
        float f2=bf2f(hsc[(size_t)i2*64+c]), f3=bf2f(hsc[(size_t)i3*64+c]);
        a += (f0+f1)+(f2+f3);
      }
      for (; e<e1; ++e) a += bf2f(hsc[(size_t)csr[e]*64+c]);
      acc[j] += a;
      E[j] = e1;
    }
  }
  float s1 = 0.f, s2 = 0.f;
  #pragma unroll
  for (int j=0; j<13; ++j){
    int idx = local + j*1024;
    if (idx < NN/8){
      int v = vb + idx;
      float o = acc[j]*dinv[v] + bc;
      __builtin_nontemporal_store(o, &out[(size_t)v*64+c]);   // keep L2 for hs
      s1 += o; s2 += o*o;
    }
  }
  __shared__ float l1[256], l2[256];
  l1[t]=s1; l2[t]=s2; __syncthreads();
  if (t < 64){
    float a1 = l1[t]+l1[t+64]+l1[t+128]+l1[t+192];
    float a2 = l2[t]+l2[t+64]+l2[t+128]+l2[t+192];
    float* rep = stats + (size_t)(blockIdx.x & 31)*128;
    atomicAdd(&rep[t],    a1);
    atomicAdd(&rep[64+t], a2);
  }
}

// ---------------- BN coeff ----------------

__global__ void k_bncoeff(const float* __restrict__ stats, const float* __restrict__ g,
                          const float* __restrict__ be, float cnt, float* __restrict__ coeff){
  int c = threadIdx.x;                       // 64
  float s1=0.f, s2=0.f;
  for (int r=0;r<32;++r){ s1 += stats[r*128+c]; s2 += stats[r*128+64+c]; }
  float mu  = s1/cnt;
  float var = s2/cnt - mu*mu;
  float a   = g[c]*rsqrtf(var + 1e-5f);
  coeff[c]    = a;
  coeff[64+c] = be[c] - mu*a;
}

// ---------------- fused pool (bounds search + BN+ReLU + mean) + W1 matmul + stats ----------------

__global__ __launch_bounds__(256) void k_poolhead(const float* __restrict__ h,
    const int* __restrict__ batch, const float* __restrict__ cf,
    const float* __restrict__ W1, const float* __restrict__ b1,
    float* __restrict__ tbuf, float* __restrict__ stats){
  __shared__ float pl[256];
  int t=threadIdx.x; int c=t&63; int wv=t>>6;
  int g = __builtin_amdgcn_readfirstlane((int)(blockIdx.x*4 + wv));
  int lo=0, hi=NN;
  while (lo<hi){ int mid=(lo+hi)>>1; if (batch[mid]<g) lo=mid+1; else hi=mid; }
  int s = lo;
  hi = NN;
  while (lo<hi){ int mid=(lo+hi)>>1; if (batch[mid]<g+1) lo=mid+1; else hi=mid; }
  int e = lo;
  float a = cf[c], d = cf[64+c];
  float acc=0.f;
  for (int v=s; v<e; ++v) acc += fmaxf(fmaf(h[(size_t)v*64+c], a, d), 0.f);
  float inv = 1.0f / fmaxf((float)(e-s), 1.0f);
  pl[wv*64 + c] = acc*inv;
  __syncthreads();
  const float* p = pl + wv*64;
  float tk = b1[c];
  #pragma unroll 4
  for (int k=0;k<64;++k) tk = fmaf(p[k], W1[k*64+c], tk);
  tbuf[(size_t)g*64+c] = tk;
  float* rep = stats + (size_t)(blockIdx.x & 31)*128;
  atomicAdd(&rep[c],    tk);
  atomicAdd(&rep[64+c], tk*tk);
}

__global__ __launch_bounds__(256) void k_final(const float* __restrict__ tbuf, const float* __restrict__ gcf,
                                               const float* __restrict__ W2, const float* __restrict__ b2,
                                               float* __restrict__ out){
  int t=threadIdx.x; int c=t&63;
  int g = blockIdx.x*4 + (t>>6);
  float tv = tbuf[(size_t)g*64+c];
  float z  = fmaxf(fmaf(tv, gcf[c], gcf[64+c]), 0.f);
  float p  = z * W2[c];
  #pragma unroll
  for (int o=32;o>0;o>>=1) p += __shfl_xor(p, o, 64);
  if (c==0) out[g] = p + b2[0];
}

// ---------------- launch ----------------

extern "C" void kernel_launch(void* const* d_in, const int* in_sizes, int n_in,
                              void* d_out, int out_size, void* d_ws, size_t ws_size,
                              hipStream_t stream) {
  const float* x    = (const float*)d_in[0];
  const int*   ei   = (const int*)d_in[1];
  const int*   batch= (const int*)d_in[2];
  const float* Wc0=(const float*)d_in[3],  *bc0=(const float*)d_in[4];
  const float* g0 =(const float*)d_in[5],  *be0=(const float*)d_in[6];
  const float* Wc1=(const float*)d_in[7],  *bc1=(const float*)d_in[8];
  const float* g1 =(const float*)d_in[9],  *be1=(const float*)d_in[10];
  const float* Wc2=(const float*)d_in[11], *bc2=(const float*)d_in[12];
  const float* g2 =(const float*)d_in[13], *be2=(const float*)d_in[14];
  const float* W1 =(const float*)d_in[15], *b1 =(const float*)d_in[16];
  const float* gf =(const float*)d_in[17], *bf_=(const float*)d_in[18];
  const float* W2 =(const float*)d_in[19], *b2 =(const float*)d_in[20];
  float* out = (float*)d_out;

  // Packed layout, total 53,121,552 B — identical footprint to the
  // previously-passing map (round-0's +3.2 MB growth correlated with the
  // container crash; csr as ushort frees the room for colptrC instead).
  char* w = (char*)d_ws;
  float*    stats  = (float*)   (w + 0);          // 4 sets x 32 reps x 128 f [zeroed]
  int*      total  = (int*)     (w + 65536);      // NBK
  int*      base   = (int*)     (w + 68736);      // NBK+1
  float*    dinv   = (float*)   (w + 71936);      // NN floats       (ends 471,936)
  float*    coeff  = (float*)   (w + 471952);
  float*    gcoeff = (float*)   (w + 472464);
  float*    pooled = (float*)   (w + 472976);     // NG x 64         (ends 1,521,552)
  int*      colptrC= (int*)     (w + 1521552);    // NN x 8          (ends 4,721,552)
  ushort_t* csr    = (ushort_t*)(w + 4721552);    // NE ushorts      (ends 11,121,552)
  int*      histT  = (int*)     (w + 11121552);   // NBK x NB        (ends 11,922,320)
  ushort_t* bufA   = (ushort_t*)(w + 14721552);   // hs bf16 row-major (ends 27,521,552)
  float*    bufB   = (float*)   (w + 27521552);   // h fp32 row-major  (ends 53,121,552)
  int*      pairs  = (int*)bufB;                  // alias: dead before bufB first write

  hipMemsetAsync(stats, 0, 65536, stream);

  // CSR build (no global atomics), rows chunk-sorted, chunk-relative ushort
  k_hist <<<NB,  512,  0, stream>>>(ei, histT);
  k_scanA<<<196, 256,  0, stream>>>(histT, total);
  k_scanB<<<1,   1024, 0, stream>>>(total, base);
  k_pairs<<<NB,  512,  0, stream>>>(ei, histT, base, pairs);
  k_fine <<<NBK, 256,  0, stream>>>(pairs, base, csr, colptrC, dinv);

  // layer 0
  k_gemm0m<<<1563, 256, 0, stream>>>(x, Wc0, dinv, bufA);
  k_aggregate<<<2048, 256, 0, stream>>>(bufA, colptrC, csr, dinv, bc0, bufB, stats + 0*4096);
  k_bncoeff<<<1, 64, 0, stream>>>(stats + 0*4096, g0, be0, (float)NN, coeff);
  // layer 1 (BN+ReLU of layer 0 fused into A-path)
  k_gemmSm<<<1563, 256, 0, stream>>>(bufB, Wc1, coeff, dinv, bufA);
  k_aggregate<<<2048, 256, 0, stream>>>(bufA, colptrC, csr, dinv, bc1, bufB, stats + 1*4096);
  k_bncoeff<<<1, 64, 0, stream>>>(stats + 1*4096, g1, be1, (float)NN, coeff);
  // layer 2
  k_gemmSm<<<1563, 256, 0, stream>>>(bufB, Wc2, coeff, dinv, bufA);
  k_aggregate<<<2048, 256, 0, stream>>>(bufA, colptrC, csr, dinv, bc2, bufB, stats + 2*4096);
  k_bncoeff<<<1, 64, 0, stream>>>(stats + 2*4096, g2, be2, (float)NN, coeff);

  // head (BN+ReLU of layer 2 + bounds search + mean + W1 fused)
  k_poolhead<<<NG/4, 256, 0, stream>>>(bufB, batch, coeff, W1, b1, pooled, stats + 3*4096);
  k_bncoeff<<<1, 64, 0, stream>>>(stats + 3*4096, gf, bf_, (float)NG, gcoeff);
  k_final<<<NG/4, 256, 0, stream>>>(pooled, gcoeff, W2, b2, out);
}

// Round 5
// 707.386 us; speedup vs baseline: 2.1098x; 1.3460x over previous
//
#include <hip/hip_runtime.h>
#include <hip/hip_bf16.h>

#define NN 100000
#define NE 3200000
#define NG 4096
#define NB 256          // blocks in hist/pairs; NE/NB = 12500 exactly
#define NBK 782         // coarse buckets of 128 nodes
#define NCHUNK 4        // src chunks of 25000 nodes (3.2 MB of hs each)
#define CHN 25000
#define SENT 0xFFFF
#define BSLACK 1540     // per-bucket csr slack: 512 keys*3 pads + align

typedef unsigned short ushort_t;
typedef short short8 __attribute__((ext_vector_type(8)));
typedef float floatx4 __attribute__((ext_vector_type(4)));

__device__ __forceinline__ float bf2f(unsigned short u){
  union{unsigned int i; float f;} x; x.i = ((unsigned)u)<<16; return x.f;
}
__device__ __forceinline__ ushort_t f2bf(float f){
  union{float f; unsigned int i;} x; x.f = f;
  unsigned int r = x.i + 0x7fff + ((x.i >> 16) & 1);
  return (ushort_t)(r >> 16);
}
// chunk id for src<100000: floor(src/25000) via magic mul (verified exact at
// boundaries 24999/25000, 49999/50000, 74999/75000, 99999)
__device__ __forceinline__ unsigned chunk_of(int src){
  return ((unsigned)src * 21475u) >> 29;
}

// ---------------- CSR build: hierarchical counting sort ----------------

__global__ __launch_bounds__(512) void k_hist(const int* __restrict__ ei, int* __restrict__ histT){
  __shared__ int lh[NBK];
  int b = blockIdx.x, t = threadIdx.x;
  for (int k=t; k<NBK; k+=512) lh[k]=0;
  __syncthreads();
  int e0 = b*(NE/NB);
  for (int e=e0+t; e<e0+(NE/NB); e+=512) atomicAdd(&lh[ei[NE+e]>>7], 1);
  __syncthreads();
  for (int k=t; k<NBK; k+=512) histT[(size_t)k*NB+b] = lh[k];
}

__global__ __launch_bounds__(256) void k_scanA(int* __restrict__ histT, int* __restrict__ total){
  int wv = blockIdx.x*4 + (threadIdx.x>>6);
  int lane = threadIdx.x & 63;
  if (wv >= NBK) return;
  int* row = histT + (size_t)wv*NB;
  int carry = 0;
  #pragma unroll
  for (int ch=0; ch<NB/64; ++ch){
    int a = row[ch*64+lane];
    int inc = a;
    for (int off=1; off<64; off<<=1){
      int x = __shfl_up(inc, off, 64);
      if (lane >= off) inc += x;
    }
    row[ch*64+lane] = carry + inc - a;       // exclusive
    carry += __shfl(inc, 63, 64);
  }
  if (lane==0) total[wv] = carry;
}

__global__ void k_scanB(const int* __restrict__ total, int* __restrict__ base){
  __shared__ int lds[1024];
  int t = threadIdx.x;
  int v = (t < NBK)? total[t] : 0;
  lds[t] = v; __syncthreads();
  for (int off=1; off<1024; off<<=1){
    int x = (t>=off)? lds[t-off] : 0;
    __syncthreads();
    lds[t] += x;
    __syncthreads();
  }
  if (t < NBK)      base[t]   = lds[t]-v;
  if (t == NBK-1)   base[NBK] = lds[t];      // == NE
}

__global__ __launch_bounds__(512) void k_pairs(const int* __restrict__ ei,
    const int* __restrict__ histT, const int* __restrict__ base,
    int* __restrict__ pairs){
  __shared__ int cur[NBK];
  int b = blockIdx.x, t = threadIdx.x;
  for (int k=t; k<NBK; k+=512) cur[k] = base[k] + histT[(size_t)k*NB + b];
  __syncthreads();
  int e0 = b*(NE/NB);
  for (int e=e0+t; e<e0+(NE/NB); e+=512){
    int src = ei[e], dst = ei[NE+e];
    int p = atomicAdd(&cur[dst>>7], 1);      // LDS atomic
    pairs[p] = (src << 7) | (dst & 127);
  }
}

// per-bucket 9-bit counting sort ((dst&127)<<2 | src_chunk) -> csr stored as
// CHUNK-RELATIVE ushort, with every (node,chunk) segment PADDED to a multiple
// of 4 entries using SENT (0xFFFF). colptrC[v*8+ch] = segment starts,
// [v*8+4] = row end. Padding -> branch-free counted 4-wide aggregate loops.
__global__ __launch_bounds__(256) void k_fine(const int* __restrict__ pairs,
    const int* __restrict__ base, ushort_t* __restrict__ csr,
    int* __restrict__ colptrC, float* __restrict__ dinv){
  __shared__ int cnt[512], off[512], part[256];
  int k = blockIdx.x, t = threadIdx.x;
  for (int i=t; i<512; i+=256) cnt[i]=0;
  __syncthreads();
  int s = base[k], e = base[k+1];
  for (int i=s+t; i<e; i+=256){
    int u = pairs[i];
    int src = u >> 7;
    atomicAdd(&cnt[((u & 127) << 2) | chunk_of(src)], 1);
  }
  __syncthreads();
  // exclusive scan of the 512 PAD4 counts: 2/thread + 256-wide Hillis-Steele
  int c0 = cnt[2*t], c1 = cnt[2*t+1];
  int p0 = (c0+3)&~3, p1 = (c1+3)&~3;
  int loc = p0+p1;
  part[t] = loc;
  __syncthreads();
  for (int o=1; o<256; o<<=1){
    int x = (t>=o)? part[t-o] : 0;
    __syncthreads();
    part[t] += x;
    __syncthreads();
  }
  int ex = part[t] - loc;
  off[2*t]   = ex;
  off[2*t+1] = ex + p0;
  __syncthreads();
  int pb = (base[k] + k*BSLACK + 3) & ~3;    // padded bucket base, x4 aligned
  int node0 = k*128;
  if (t < 128 && node0+t < NN){
    int key = t*4;
    int o3 = off[key+3];
    int c3 = cnt[key+3];
    int v = node0 + t;
    colptrC[(size_t)v*8+0] = pb + off[key];
    colptrC[(size_t)v*8+1] = pb + off[key+1];
    colptrC[(size_t)v*8+2] = pb + off[key+2];
    colptrC[(size_t)v*8+3] = pb + o3;
    colptrC[(size_t)v*8+4] = pb + o3 + ((c3+3)&~3);     // row end
    int raw = cnt[key]+cnt[key+1]+cnt[key+2]+c3;
    dinv[v] = rsqrtf((float)raw + 1.0f);
  }
  __syncthreads();
  // sentinel-fill the pad slots (before off[] becomes scatter cursors)
  for (int i=t; i<512; i+=256){
    int cc = cnt[i], pe = (cc+3)&~3;
    int b0 = pb + off[i] + cc;
    for (int p=0; p<pe-cc; ++p) csr[b0+p] = SENT;
  }
  __syncthreads();
  for (int i=s+t; i<e; i+=256){
    int u = pairs[i];
    int src = u >> 7;
    unsigned ch = chunk_of(src);
    int key = ((u & 127) << 2) | ch;
    int p = pb + atomicAdd(&off[key], 1);
    csr[p] = (ushort_t)(src - (int)ch*CHN);  // chunk-relative, < 25000
  }
}

// ---------------- MFMA GEMM layer 0: hs = bf16( (x @ W) * dinv ), K=128 ----------------

__global__ __launch_bounds__(256) void k_gemm0m(const float* __restrict__ x,
    const float* __restrict__ W, const float* __restrict__ dinv,
    ushort_t* __restrict__ hs){
  __shared__ __attribute__((aligned(16))) ushort_t Wt[64*136];
  int t = threadIdx.x;
  for (int i=t; i<128*64; i+=256){
    int k = i>>6, n = i&63;
    Wt[n*136 + k] = f2bf(W[i]);
  }
  __syncthreads();
  int lane = t & 63, wv = t >> 6;
  int n0 = lane & 15, quad = lane >> 4;
  int r0 = blockIdx.x*64 + wv*16;
  int row = r0 + n0;
  int rowc = (row < NN)? row : NN-1;
  const float* xr = x + (size_t)rowc*128 + quad*8;
  floatx4 acc[4] = {{0,0,0,0},{0,0,0,0},{0,0,0,0},{0,0,0,0}};
  #pragma unroll
  for (int ks=0; ks<4; ++ks){
    float4 a01 = *(const float4*)(xr + ks*32);
    float4 a23 = *(const float4*)(xr + ks*32 + 4);
    short8 af;
    af[0]=(short)f2bf(a01.x); af[1]=(short)f2bf(a01.y);
    af[2]=(short)f2bf(a01.z); af[3]=(short)f2bf(a01.w);
    af[4]=(short)f2bf(a23.x); af[5]=(short)f2bf(a23.y);
    af[6]=(short)f2bf(a23.z); af[7]=(short)f2bf(a23.w);
    #pragma unroll
    for (int tl=0; tl<4; ++tl){
      short8 bf = *(const short8*)(&Wt[(tl*16+n0)*136 + ks*32 + quad*8]);
      acc[tl] = __builtin_amdgcn_mfma_f32_16x16x32_bf16(af, bf, acc[tl], 0, 0, 0);
    }
  }
  #pragma unroll
  for (int reg=0; reg<4; ++reg){
    int rr = r0 + quad*4 + reg;
    if (rr < NN){
      float dv = dinv[rr];
      #pragma unroll
      for (int tl=0; tl<4; ++tl)
        hs[(size_t)rr*64 + tl*16 + n0] = f2bf(acc[tl][reg]*dv);
    }
  }
}

// ---------------- MFMA GEMM layers 1/2 with fused BN+ReLU on A, K=64 ----------------

__global__ __launch_bounds__(256) void k_gemmSm(const float* __restrict__ h,
    const float* __restrict__ W, const float* __restrict__ coeff,
    const float* __restrict__ dinv, ushort_t* __restrict__ hs){
  __shared__ __attribute__((aligned(16))) ushort_t Wt[64*72];
  int t = threadIdx.x;
  for (int i=t; i<64*64; i+=256){
    int k = i>>6, n = i&63;
    Wt[n*72 + k] = f2bf(W[i]);
  }
  __syncthreads();
  int lane = t & 63, wv = t >> 6;
  int n0 = lane & 15, quad = lane >> 4;
  int r0 = blockIdx.x*64 + wv*16;
  int row = r0 + n0;
  int rowc = (row < NN)? row : NN-1;
  const float* hr = h + (size_t)rowc*64 + quad*8;
  floatx4 acc[4] = {{0,0,0,0},{0,0,0,0},{0,0,0,0},{0,0,0,0}};
  #pragma unroll
  for (int ks=0; ks<2; ++ks){
    float4 a01 = *(const float4*)(hr + ks*32);
    float4 a23 = *(const float4*)(hr + ks*32 + 4);
    const float* cA = coeff + ks*32 + quad*8;
    float4 ca0 = *(const float4*)(cA),      ca1 = *(const float4*)(cA+4);
    float4 cb0 = *(const float4*)(cA+64),   cb1 = *(const float4*)(cA+68);
    short8 af;
    af[0]=(short)f2bf(fmaxf(fmaf(a01.x,ca0.x,cb0.x),0.f));
    af[1]=(short)f2bf(fmaxf(fmaf(a01.y,ca0.y,cb0.y),0.f));
    af[2]=(short)f2bf(fmaxf(fmaf(a01.z,ca0.z,cb0.z),0.f));
    af[3]=(short)f2bf(fmaxf(fmaf(a01.w,ca0.w,cb0.w),0.f));
    af[4]=(short)f2bf(fmaxf(fmaf(a23.x,ca1.x,cb1.x),0.f));
    af[5]=(short)f2bf(fmaxf(fmaf(a23.y,ca1.y,cb1.y),0.f));
    af[6]=(short)f2bf(fmaxf(fmaf(a23.z,ca1.z,cb1.z),0.f));
    af[7]=(short)f2bf(fmaxf(fmaf(a23.w,ca1.w,cb1.w),0.f));
    #pragma unroll
    for (int tl=0; tl<4; ++tl){
      short8 bf = *(const short8*)(&Wt[(tl*16+n0)*72 + ks*32 + quad*8]);
      acc[tl] = __builtin_amdgcn_mfma_f32_16x16x32_bf16(af, bf, acc[tl], 0, 0, 0);
    }
  }
  #pragma unroll
  for (int reg=0; reg<4; ++reg){
    int rr = r0 + quad*4 + reg;
    if (rr < NN){
      float dv = dinv[rr];
      #pragma unroll
      for (int tl=0; tl<4; ++tl)
        hs[(size_t)rr*64 + tl*16 + n0] = f2bf(acc[tl][reg]*dv);
    }
  }
}

// ---------------- src-chunked pull-aggregation, padded counted loops ----------------
// Segments padded to x4 -> branch-free 4-wide counted loops (1 aligned 8B csr
// load -> 4 independent gathers; sentinel gathers clamp to row 0 and are
// masked out). Bounds come from wave-uniform s_loads; cursors E[j] carry
// across the 4 chunk passes. Each 3.2 MB hs chunk is gathered by all waves
// concurrently while L2-resident; blockIdx&7 pins each XCD to a contiguous
// 1/8 of dst nodes so its csr slice stays L2-resident.

__global__ __launch_bounds__(256) void k_aggregate(const ushort_t* __restrict__ hs,
    const int* __restrict__ colptrC, const ushort_t* __restrict__ csr,
    const float* __restrict__ dinv, const float* __restrict__ bias,
    float* __restrict__ out, float* __restrict__ stats){
  int t = threadIdx.x; int c = t & 63;
  int b = blockIdx.x;
  int xcd = b & 7;
  int local = (b>>3)*4 + (t>>6);             // 0..1023 (wave-uniform)
  int vb = xcd * (NN/8);                     // 12500 nodes per XCD slice
  float bc = bias[c];
  float acc[13];
  int E[13];
  #pragma unroll
  for (int j=0; j<13; ++j){
    int idx = local + j*1024;
    int v = __builtin_amdgcn_readfirstlane(vb + ((idx < NN/8)? idx : 0));
    acc[j] = bf2f(hs[(size_t)v*64 + c]);     // self-loop (dead slots harmless)
    E[j] = colptrC[(size_t)v*8];             // row start
  }
  for (int ch=0; ch<NCHUNK; ++ch){
    const ushort_t* hsc = hs + (size_t)(ch*CHN)*64;
    #pragma unroll
    for (int j=0; j<13; ++j){
      int idx = local + j*1024;
      int v = __builtin_amdgcn_readfirstlane(vb + ((idx < NN/8)? idx : 0));
      int e1 = colptrC[(size_t)v*8 + ch + 1];
      int e = E[j];
      float a = 0.f;
      for (; e < e1; e += 4){                // counted, padded: no remainder
        int2 pk = *(const int2*)(csr + e);   // 4 entries, 8B aligned
        int i0 = pk.x & 0xFFFF, i1 = ((unsigned)pk.x) >> 16;
        int i2 = pk.y & 0xFFFF, i3 = ((unsigned)pk.y) >> 16;
        int i0c = (i0 != SENT)? i0 : 0;
        int i1c = (i1 != SENT)? i1 : 0;
        int i2c = (i2 != SENT)? i2 : 0;
        int i3c = (i3 != SENT)? i3 : 0;
        float f0 = bf2f(hsc[(size_t)i0c*64+c]);
        float f1 = bf2f(hsc[(size_t)i1c*64+c]);
        float f2 = bf2f(hsc[(size_t)i2c*64+c]);
        float f3 = bf2f(hsc[(size_t)i3c*64+c]);
        f0 = (i0 != SENT)? f0 : 0.f;
        f1 = (i1 != SENT)? f1 : 0.f;
        f2 = (i2 != SENT)? f2 : 0.f;
        f3 = (i3 != SENT)? f3 : 0.f;
        a += (f0+f1)+(f2+f3);
      }
      acc[j] += a;
      E[j] = e1;
    }
  }
  float s1 = 0.f, s2 = 0.f;
  #pragma unroll
  for (int j=0; j<13; ++j){
    int idx = local + j*1024;
    if (idx < NN/8){
      int v = vb + idx;
      float o = acc[j]*dinv[v] + bc;
      __builtin_nontemporal_store(o, &out[(size_t)v*64+c]);   // keep L2 for hs
      s1 += o; s2 += o*o;
    }
  }
  __shared__ float l1[256], l2[256];
  l1[t]=s1; l2[t]=s2; __syncthreads();
  if (t < 64){
    float a1 = l1[t]+l1[t+64]+l1[t+128]+l1[t+192];
    float a2 = l2[t]+l2[t+64]+l2[t+128]+l2[t+192];
    float* rep = stats + (size_t)(blockIdx.x & 31)*128;
    atomicAdd(&rep[t],    a1);
    atomicAdd(&rep[64+t], a2);
  }
}

// ---------------- BN coeff ----------------

__global__ void k_bncoeff(const float* __restrict__ stats, const float* __restrict__ g,
                          const float* __restrict__ be, float cnt, float* __restrict__ coeff){
  int c = threadIdx.x;                       // 64
  float s1=0.f, s2=0.f;
  for (int r=0;r<32;++r){ s1 += stats[r*128+c]; s2 += stats[r*128+64+c]; }
  float mu  = s1/cnt;
  float var = s2/cnt - mu*mu;
  float a   = g[c]*rsqrtf(var + 1e-5f);
  coeff[c]    = a;
  coeff[64+c] = be[c] - mu*a;
}

// ---------------- fused pool (bounds search + BN+ReLU + mean) + W1 matmul + stats ----------------

__global__ __launch_bounds__(256) void k_poolhead(const float* __restrict__ h,
    const int* __restrict__ batch, const float* __restrict__ cf,
    const float* __restrict__ W1, const float* __restrict__ b1,
    float* __restrict__ tbuf, float* __restrict__ stats){
  __shared__ float pl[256];
  int t=threadIdx.x; int c=t&63; int wv=t>>6;
  int g = __builtin_amdgcn_readfirstlane((int)(blockIdx.x*4 + wv));
  int lo=0, hi=NN;
  while (lo<hi){ int mid=(lo+hi)>>1; if (batch[mid]<g) lo=mid+1; else hi=mid; }
  int s = lo;
  hi = NN;
  while (lo<hi){ int mid=(lo+hi)>>1; if (batch[mid]<g+1) lo=mid+1; else hi=mid; }
  int e = lo;
  float a = cf[c], d = cf[64+c];
  float acc=0.f;
  for (int v=s; v<e; ++v) acc += fmaxf(fmaf(h[(size_t)v*64+c], a, d), 0.f);
  float inv = 1.0f / fmaxf((float)(e-s), 1.0f);
  pl[wv*64 + c] = acc*inv;
  __syncthreads();
  const float* p = pl + wv*64;
  float tk = b1[c];
  #pragma unroll 4
  for (int k=0;k<64;++k) tk = fmaf(p[k], W1[k*64+c], tk);
  tbuf[(size_t)g*64+c] = tk;
  float* rep = stats + (size_t)(blockIdx.x & 31)*128;
  atomicAdd(&rep[c],    tk);
  atomicAdd(&rep[64+c], tk*tk);
}

__global__ __launch_bounds__(256) void k_final(const float* __restrict__ tbuf, const float* __restrict__ gcf,
                                               const float* __restrict__ W2, const float* __restrict__ b2,
                                               float* __restrict__ out){
  int t=threadIdx.x; int c=t&63;
  int g = blockIdx.x*4 + (t>>6);
  float tv = tbuf[(size_t)g*64+c];
  float z  = fmaxf(fmaf(tv, gcf[c], gcf[64+c]), 0.f);
  float p  = z * W2[c];
  #pragma unroll
  for (int o=32;o>0;o>>=1) p += __shfl_xor(p, o, 64);
  if (c==0) out[g] = p + b2[0];
}

// ---------------- launch ----------------

extern "C" void kernel_launch(void* const* d_in, const int* in_sizes, int n_in,
                              void* d_out, int out_size, void* d_ws, size_t ws_size,
                              hipStream_t stream) {
  const float* x    = (const float*)d_in[0];
  const int*   ei   = (const int*)d_in[1];
  const int*   batch= (const int*)d_in[2];
  const float* Wc0=(const float*)d_in[3],  *bc0=(const float*)d_in[4];
  const float* g0 =(const float*)d_in[5],  *be0=(const float*)d_in[6];
  const float* Wc1=(const float*)d_in[7],  *bc1=(const float*)d_in[8];
  const float* g1 =(const float*)d_in[9],  *be1=(const float*)d_in[10];
  const float* Wc2=(const float*)d_in[11], *bc2=(const float*)d_in[12];
  const float* g2 =(const float*)d_in[13], *be2=(const float*)d_in[14];
  const float* W1 =(const float*)d_in[15], *b1 =(const float*)d_in[16];
  const float* gf =(const float*)d_in[17], *bf_=(const float*)d_in[18];
  const float* W2 =(const float*)d_in[19], *b2 =(const float*)d_in[20];
  float* out = (float*)d_out;

  // Packed layout, total 53,121,552 B — byte-identical footprint to the
  // round-2/3 PASSING runs (bufA/bufB at their proven offsets).
  char* w = (char*)d_ws;
  float*    stats  = (float*)   (w + 0);          // 4 sets x 32 reps x 128 f [zeroed]
  int*      total  = (int*)     (w + 65536);      // NBK
  int*      base   = (int*)     (w + 68736);      // NBK+1
  float*    dinv   = (float*)   (w + 71936);      // NN floats      (ends 471,936)
  float*    coeff  = (float*)   (w + 471952);
  float*    gcoeff = (float*)   (w + 472464);
  float*    pooled = (float*)   (w + 472976);     // NG x 64        (ends 1,521,552)
  int*      colptrC= (int*)     (w + 1521552);    // NN x 8 ints    (ends 4,721,552)
  ushort_t* csr    = (ushort_t*)(w + 4721552);    // padded: <= 8,808,624 B (ends 13,530,176)
  int*      histT  = (int*)     (w + 13530176);   // NBK x NB ints  (ends 14,330,944)
  ushort_t* bufA   = (ushort_t*)(w + 14721552);   // hs bf16 row-major (proven offset)
  float*    bufB   = (float*)   (w + 27521552);   // h fp32 row-major  (ends 53,121,552)
  int*      pairs  = (int*)bufB;                  // alias: dead before bufB first write

  hipMemsetAsync(stats, 0, 65536, stream);

  // CSR build (no global atomics): chunk-sorted rows, x4-padded segments
  k_hist <<<NB,  512,  0, stream>>>(ei, histT);
  k_scanA<<<196, 256,  0, stream>>>(histT, total);
  k_scanB<<<1,   1024, 0, stream>>>(total, base);
  k_pairs<<<NB,  512,  0, stream>>>(ei, histT, base, pairs);
  k_fine <<<NBK, 256,  0, stream>>>(pairs, base, csr, colptrC, dinv);

  // layer 0
  k_gemm0m<<<1563, 256, 0, stream>>>(x, Wc0, dinv, bufA);
  k_aggregate<<<2048, 256, 0, stream>>>(bufA, colptrC, csr, dinv, bc0, bufB, stats + 0*4096);
  k_bncoeff<<<1, 64, 0, stream>>>(stats + 0*4096, g0, be0, (float)NN, coeff);
  // layer 1 (BN+ReLU of layer 0 fused into A-path)
  k_gemmSm<<<1563, 256, 0, stream>>>(bufB, Wc1, coeff, dinv, bufA);
  k_aggregate<<<2048, 256, 0, stream>>>(bufA, colptrC, csr, dinv, bc1, bufB, stats + 1*4096);
  k_bncoeff<<<1, 64, 0, stream>>>(stats + 1*4096, g1, be1, (float)NN, coeff);
  // layer 2
  k_gemmSm<<<1563, 256, 0, stream>>>(bufB, Wc2, coeff, dinv, bufA);
  k_aggregate<<<2048, 256, 0, stream>>>(bufA, colptrC, csr, dinv, bc2, bufB, stats + 2*4096);
  k_bncoeff<<<1, 64, 0, stream>>>(stats + 2*4096, g2, be2, (float)NN, coeff);

  // head (BN+ReLU of layer 2 + bounds search + mean + W1 fused)
  k_poolhead<<<NG/4, 256, 0, stream>>>(bufB, batch, coeff, W1, b1, pooled, stats + 3*4096);
  k_bncoeff<<<1, 64, 0, stream>>>(stats + 3*4096, gf, bf_, (float)NG, gcoeff);
  k_final<<<NG/4, 256, 0, stream>>>(pooled, gcoeff, W2, b2, out);
}